// Round 3
// baseline (3544.841 us; speedup 1.0000x reference)
//
#include <hip/hip_runtime.h>
#include <math.h>

#define QLEN 900
#define CDIM 256
#define BATCH 8
#define NTOK (BATCH * QLEN)   // 7200

// ---------------------------------------------------------------------------
// Transpose [B,C,Q] -> [B,Q,C] for tgt and query_pos; also qk = tgt + qp.
// ---------------------------------------------------------------------------
__global__ void transpose_in_k(const float* __restrict__ tgt, const float* __restrict__ qp,
                               float* __restrict__ tgt_tok, float* __restrict__ qp_tok,
                               float* __restrict__ qk_tok) {
  __shared__ float t0[32][33];
  __shared__ float t1[32][33];
  const int b  = blockIdx.z;
  const int c0 = blockIdx.y * 32;
  const int q0 = blockIdx.x * 32;
  const int tx = threadIdx.x, ty = threadIdx.y;
  const int q = q0 + tx;
  if (q < QLEN) {
    long i = ((long)(b * CDIM + c0 + ty)) * QLEN + q;
    t0[ty][tx] = tgt[i];
    t1[ty][tx] = qp[i];
  }
  __syncthreads();
  const int qo = q0 + ty;
  if (qo < QLEN) {
    long o = ((long)(b * QLEN + qo)) * CDIM + c0 + tx;
    float a = t0[tx][ty], p = t1[tx][ty];
    tgt_tok[o] = a;
    qp_tok[o]  = p;
    qk_tok[o]  = a + p;
  }
}

// ---------------------------------------------------------------------------
// GEMM: Out[m][n] = sum_k A(m,k) * W[n][k] + bias[n]   (optionally ReLU)
// ACHAN=0: A row-major [M,K] (token-major)
// ACHAN=1: A(m,k) = A[k*ldA + m] (channel-major input image, single batch)
// Tile: 128(M) x 64(N) x 16(K), 256 threads, 8x4 micro-tile per thread.
// ---------------------------------------------------------------------------
template <int ACHAN>
__global__ __launch_bounds__(256) void gemm_k(
    const float* __restrict__ A, const float* __restrict__ W,
    const float* __restrict__ bias, float* __restrict__ Out,
    int M, int N, int K, int ldA, int relu) {
  __shared__ float As[16][128];
  __shared__ float Bs[16][64];
  const int m0 = blockIdx.x * 128, n0 = blockIdx.y * 64;
  const int tid = threadIdx.x;
  const int tx = tid & 15, ty = tid >> 4;
  float acc[8][4];
#pragma unroll
  for (int j = 0; j < 8; ++j)
#pragma unroll
    for (int i = 0; i < 4; ++i) acc[j][i] = 0.f;

  for (int k0 = 0; k0 < K; k0 += 16) {
    if (ACHAN) {
      const int mi = tid & 127;
      const int kk0 = (tid >> 7) * 8;
      const int m = m0 + mi;
#pragma unroll
      for (int j = 0; j < 8; ++j) {
        float v = 0.f;
        if (m < M) v = A[(long)(k0 + kk0 + j) * ldA + m];
        As[kk0 + j][mi] = v;
      }
    } else {
      const int mi = tid >> 1;
      const int k8 = (tid & 1) * 8;
      const int m = m0 + mi;
      float4 v0 = make_float4(0.f, 0.f, 0.f, 0.f), v1 = v0;
      if (m < M) {
        const float4* p = (const float4*)&A[(long)m * K + k0 + k8];
        v0 = p[0];
        v1 = p[1];
      }
      As[k8 + 0][mi] = v0.x; As[k8 + 1][mi] = v0.y;
      As[k8 + 2][mi] = v0.z; As[k8 + 3][mi] = v0.w;
      As[k8 + 4][mi] = v1.x; As[k8 + 5][mi] = v1.y;
      As[k8 + 6][mi] = v1.z; As[k8 + 7][mi] = v1.w;
    }
    {
      const int ni = tid >> 2;
      const int k4 = (tid & 3) * 4;
      const float4 v = *(const float4*)&W[(long)(n0 + ni) * K + k0 + k4];
      Bs[k4 + 0][ni] = v.x; Bs[k4 + 1][ni] = v.y;
      Bs[k4 + 2][ni] = v.z; Bs[k4 + 3][ni] = v.w;
    }
    __syncthreads();
#pragma unroll
    for (int kk = 0; kk < 16; ++kk) {
      float a[8];
#pragma unroll
      for (int j = 0; j < 8; ++j) a[j] = As[kk][ty + 16 * j];
      const float4 b4 = *(const float4*)&Bs[kk][tx * 4];
      const float bv[4] = {b4.x, b4.y, b4.z, b4.w};
#pragma unroll
      for (int j = 0; j < 8; ++j)
#pragma unroll
        for (int i = 0; i < 4; ++i) acc[j][i] += a[j] * bv[i];
    }
    __syncthreads();
  }
  const float4 bb = *(const float4*)&bias[n0 + tx * 4];
#pragma unroll
  for (int j = 0; j < 8; ++j) {
    const int m = m0 + ty + 16 * j;
    if (m < M) {
      float4 o;
      o.x = acc[j][0] + bb.x; o.y = acc[j][1] + bb.y;
      o.z = acc[j][2] + bb.z; o.w = acc[j][3] + bb.w;
      if (relu) {
        o.x = fmaxf(o.x, 0.f); o.y = fmaxf(o.y, 0.f);
        o.z = fmaxf(o.z, 0.f); o.w = fmaxf(o.w, 0.f);
      }
      *(float4*)&Out[(long)m * N + n0 + tx * 4] = o;
    }
  }
}

// ---------------------------------------------------------------------------
// Fused MHA (flash-style, per-thread online softmax). One thread = one query.
// ---------------------------------------------------------------------------
__global__ __launch_bounds__(256) void attn_k(const float* __restrict__ Q,
                                              const float* __restrict__ K,
                                              const float* __restrict__ V,
                                              float* __restrict__ O) {
  __shared__ float Kt[128][32];
  __shared__ float Vt[128][32];
  const int b = blockIdx.z, h = blockIdx.y;
  const int q = blockIdx.x * 256 + threadIdx.x;
  const bool valid = q < QLEN;
  float qv[32];
  if (valid) {
    const float4* qp4 = (const float4*)&Q[((long)(b * QLEN + q)) * CDIM + h * 32];
#pragma unroll
    for (int i = 0; i < 8; ++i) {
      float4 t = qp4[i];
      qv[4 * i + 0] = t.x; qv[4 * i + 1] = t.y;
      qv[4 * i + 2] = t.z; qv[4 * i + 3] = t.w;
    }
  }
  float mrun = -1e30f, lsum = 0.f;
  float o[32];
#pragma unroll
  for (int d = 0; d < 32; ++d) o[d] = 0.f;

  for (int k0 = 0; k0 < QLEN; k0 += 128) {
    const int kn = min(128, QLEN - k0);
    {
      const int kr = threadIdx.x >> 1;
      const int cb = (threadIdx.x & 1) * 16;
      if (kr < kn) {
        const float4* kp = (const float4*)&K[((long)(b * QLEN + k0 + kr)) * CDIM + h * 32 + cb];
        const float4* vp = (const float4*)&V[((long)(b * QLEN + k0 + kr)) * CDIM + h * 32 + cb];
#pragma unroll
        for (int i = 0; i < 4; ++i) {
          *(float4*)&Kt[kr][cb + 4 * i] = kp[i];
          *(float4*)&Vt[kr][cb + 4 * i] = vp[i];
        }
      }
    }
    __syncthreads();
    if (valid) {
      for (int kk = 0; kk < kn; ++kk) {
        float s0 = 0.f, s1 = 0.f, s2 = 0.f, s3 = 0.f;
        const float* kr = Kt[kk];
#pragma unroll
        for (int d = 0; d < 32; d += 4) {
          s0 += qv[d + 0] * kr[d + 0];
          s1 += qv[d + 1] * kr[d + 1];
          s2 += qv[d + 2] * kr[d + 2];
          s3 += qv[d + 3] * kr[d + 3];
        }
        float s = ((s0 + s1) + (s2 + s3)) * 0.17677669529663687f; // 1/sqrt(32)
        if (s > mrun) {
          const float corr = __expf(mrun - s);
          lsum *= corr;
#pragma unroll
          for (int d = 0; d < 32; ++d) o[d] *= corr;
          mrun = s;
        }
        const float p = __expf(s - mrun);
        lsum += p;
        const float* vr = Vt[kk];
#pragma unroll
        for (int d = 0; d < 32; ++d) o[d] += p * vr[d];
      }
    }
    __syncthreads();
  }
  if (valid) {
    const float inv = 1.f / lsum;
    float* op = &O[((long)(b * QLEN + q)) * CDIM + h * 32];
#pragma unroll
    for (int i = 0; i < 8; ++i) {
      float4 t;
      t.x = o[4 * i + 0] * inv; t.y = o[4 * i + 1] * inv;
      t.z = o[4 * i + 2] * inv; t.w = o[4 * i + 3] * inv;
      ((float4*)op)[i] = t;
    }
  }
}

// ---------------------------------------------------------------------------
// LayerNorm over channel dim (token-major rows of 256). out = LN(A+B)*g+beta.
// One wave (64 lanes) per token, 4 tokens per 256-thread block.
// ---------------------------------------------------------------------------
__device__ __forceinline__ void ln_core(const float* __restrict__ A, const float* __restrict__ B,
                                        const float* __restrict__ g, const float* __restrict__ beta,
                                        int tok, int lane, float4& ov, int& c) {
  const float4 av = ((const float4*)&A[(long)tok * CDIM])[lane];
  const float4 bv = ((const float4*)&B[(long)tok * CDIM])[lane];
  const float v0 = av.x + bv.x, v1 = av.y + bv.y, v2 = av.z + bv.z, v3 = av.w + bv.w;
  float s  = v0 + v1 + v2 + v3;
  float ss = v0 * v0 + v1 * v1 + v2 * v2 + v3 * v3;
#pragma unroll
  for (int off = 32; off >= 1; off >>= 1) {
    s  += __shfl_xor(s, off);
    ss += __shfl_xor(ss, off);
  }
  const float mean = s * (1.f / 256.f);
  const float var  = ss * (1.f / 256.f) - mean * mean;
  const float inv  = 1.f / sqrtf(var + 1e-5f);
  c = lane * 4;
  const float4 gv = ((const float4*)g)[lane];
  const float4 bt = ((const float4*)beta)[lane];
  ov.x = (v0 - mean) * inv * gv.x + bt.x;
  ov.y = (v1 - mean) * inv * gv.y + bt.y;
  ov.z = (v2 - mean) * inv * gv.z + bt.z;
  ov.w = (v3 - mean) * inv * gv.w + bt.w;
}

__global__ void ln_k(const float* __restrict__ A, const float* __restrict__ B,
                     const float* __restrict__ g, const float* __restrict__ beta,
                     float* __restrict__ out) {
  const int tok = blockIdx.x * 4 + (threadIdx.x >> 6);
  const int lane = threadIdx.x & 63;
  float4 ov; int c;
  ln_core(A, B, g, beta, tok, lane, ov, c);
  ((float4*)&out[(long)tok * CDIM])[lane] = ov;
}

// Final LN: writes channel-major output [B,C,1,Q].
__global__ void ln_out_k(const float* __restrict__ A, const float* __restrict__ B,
                         const float* __restrict__ g, const float* __restrict__ beta,
                         float* __restrict__ out) {
  const int tok = blockIdx.x * 4 + (threadIdx.x >> 6);
  const int lane = threadIdx.x & 63;
  float4 ov; int c;
  ln_core(A, B, g, beta, tok, lane, ov, c);
  const int b = tok / QLEN, q = tok - b * QLEN;
  out[((long)(b * CDIM + c + 0)) * QLEN + q] = ov.x;
  out[((long)(b * CDIM + c + 1)) * QLEN + q] = ov.y;
  out[((long)(b * CDIM + c + 2)) * QLEN + q] = ov.z;
  out[((long)(b * CDIM + c + 3)) * QLEN + q] = ov.w;
}

// ---------------------------------------------------------------------------
// q4 = a + b (elementwise, float4)
// ---------------------------------------------------------------------------
__global__ void add_k(const float* __restrict__ a, const float* __restrict__ b,
                      float* __restrict__ o, long n4) {
  const long i = (long)blockIdx.x * blockDim.x + threadIdx.x;
  if (i < n4) {
    const float4 x = ((const float4*)a)[i];
    const float4 y = ((const float4*)b)[i];
    float4 r;
    r.x = x.x + y.x; r.y = x.y + y.y; r.z = x.z + y.z; r.w = x.w + y.w;
    ((float4*)o)[i] = r;
  }
}

// ---------------------------------------------------------------------------
// Deformable bilinear sampling + aggregation for ONE batch, all 4 levels.
// pv: projected values for batch bsel, levels packed: level l at lvl_off[l],
//     layout [pix][256] (chan = h*32+d).
// off_all token-major [tok][256], col = l*64 + h*8 + p*2 + {x,y}.
// awlin token-major [tok][128], col = h*16 + l*4 + p (pre-sigmoid).
// refp [256,2,1,900]: ref[((b*32+h*4+p)*2+c)*900 + q].
// res token-major [tok][256] (chan = h*32+d); written once (no accumulation
// across launches). Block 256 = 8 groups of 32 lanes; group = one (h,q).
// ---------------------------------------------------------------------------
__global__ __launch_bounds__(256) void deform_sample_k(
    const float* __restrict__ pv, const float* __restrict__ off_all,
    const float* __restrict__ awlin, const float* __restrict__ refp,
    float* __restrict__ res, int bsel) {
  const int gidx = blockIdx.x * 8 + (threadIdx.x >> 5);
  const int d = threadIdx.x & 31;
  const int q = gidx % QLEN;
  const int h = gidx / QLEN;
  const int b = bsel;

  const int vw_[4] = {160, 80, 40, 20};
  const int vh_[4] = {92, 46, 23, 12};
  const long lvl_off_[4] = {0L, 14720L * 256, (14720L + 3680) * 256,
                            (14720L + 3680 + 920) * 256};

  const float* offrow = &off_all[(long)(b * QLEN + q) * 256];
  const float* awrow  = &awlin[(long)(b * QLEN + q) * 128];
  float acc = 0.f;
#pragma unroll
  for (int l = 0; l < 4; ++l) {
    const int vw = vw_[l], vh = vh_[l];
    const float invw = 1.f / (float)vw, invh = 1.f / (float)vh;
    const float* pvl = pv + lvl_off_[l] + h * 32 + d;
#pragma unroll
    for (int p = 0; p < 4; ++p) {
      const float ox = offrow[l * 64 + h * 8 + p * 2 + 0];
      const float oy = offrow[l * 64 + h * 8 + p * 2 + 1];
      const float rx = refp[((long)((b * 32 + h * 4 + p) * 2 + 0)) * QLEN + q];
      const float ry = refp[((long)((b * 32 + h * 4 + p) * 2 + 1)) * QLEN + q];
      float aval = awrow[h * 16 + l * 4 + p];
      aval = 1.f / (1.f + __expf(-aval));
      const float x = (rx + ox * invw) * (float)(vw - 1);
      const float y = (ry + oy * invh) * (float)(vh - 1);
      const float x0f = floorf(x), y0f = floorf(y);
      const float wx1 = x - x0f, wx0 = 1.f - wx1;
      const float wy1 = y - y0f, wy0 = 1.f - wy1;
      const int x0 = (int)x0f, y0 = (int)y0f;
      const int x1 = x0 + 1, y1 = y0 + 1;
      const bool vx0 = (x0 >= 0) & (x0 < vw);
      const bool vx1 = (x1 >= 0) & (x1 < vw);
      const bool vy0 = (y0 >= 0) & (y0 < vh);
      const bool vy1 = (y1 >= 0) & (y1 < vh);
      float s = 0.f;
      if (vx0 & vy0) s += wx0 * wy0 * pvl[(long)(y0 * vw + x0) * 256];
      if (vx1 & vy0) s += wx1 * wy0 * pvl[(long)(y0 * vw + x1) * 256];
      if (vx0 & vy1) s += wx0 * wy1 * pvl[(long)(y1 * vw + x0) * 256];
      if (vx1 & vy1) s += wx1 * wy1 * pvl[(long)(y1 * vw + x1) * 256];
      acc += aval * s;
    }
  }
  res[(long)(b * QLEN + q) * 256 + h * 32 + d] = acc;
}

// ---------------------------------------------------------------------------
extern "C" void kernel_launch(void* const* d_in, const int* in_sizes, int n_in,
                              void* d_out, int out_size, void* d_ws, size_t ws_size,
                              hipStream_t stream) {
  const float* tgt  = (const float*)d_in[0];
  const float* qpos = (const float*)d_in[1];
  const float* refp = (const float*)d_in[2];
  const float* v[4] = {(const float*)d_in[3], (const float*)d_in[4],
                       (const float*)d_in[5], (const float*)d_in[6]};
  const float* so_w = (const float*)d_in[7];
  const float* so_b = (const float*)d_in[8];
  const float* vp_w = (const float*)d_in[9];
  const float* vp_b = (const float*)d_in[10];
  const float* aw_w = (const float*)d_in[11];
  const float* aw_b = (const float*)d_in[12];
  const float* op_w = (const float*)d_in[13];
  const float* op_b = (const float*)d_in[14];
  const float* wq = (const float*)d_in[15]; const float* bq = (const float*)d_in[16];
  const float* wk = (const float*)d_in[17]; const float* bk = (const float*)d_in[18];
  const float* wv = (const float*)d_in[19]; const float* bv = (const float*)d_in[20];
  const float* wo = (const float*)d_in[21]; const float* bo = (const float*)d_in[22];
  const float* g1 = (const float*)d_in[23]; const float* b1 = (const float*)d_in[24];
  const float* g2 = (const float*)d_in[25]; const float* b2 = (const float*)d_in[26];
  const float* g3 = (const float*)d_in[27]; const float* b3 = (const float*)d_in[28];
  const float* l1w = (const float*)d_in[29]; const float* l1b = (const float*)d_in[30];
  const float* l2w = (const float*)d_in[31]; const float* l2b = (const float*)d_in[32];
  float* out = (float*)d_out;

  float* ws = (float*)d_ws;
  const long T = (long)NTOK * CDIM;  // 1,843,200 floats
  // Layout (floats):
  //   [0,7T)       : 7 token-major [NTOK][256] buffers
  //   [7T, +NTOK*128) : awlin
  //   [.., +7,372,800): big buffer = max(pv one batch all levels 5,007,360 ;
  //                                      f1 NTOK*1024 = 7,372,800)
  const long need = 7 * T + (long)NTOK * 128 + (long)NTOK * 1024;
  if (ws_size < (size_t)need * sizeof(float)) return;  // fail visibly, not fatally

  float* tgt_tok = ws + 0 * T;             // later reused as x2
  float* qp_tok  = ws + 1 * T;
  float* qk_tok  = ws + 2 * T;             // later attn_out, then res
  float* Qb      = ws + 3 * T;             // later x1
  float* Kb      = ws + 4 * T;             // later q4, then f2
  float* Vb      = ws + 5 * T;             // later off_all
  float* Ob      = ws + 6 * T;             // later ca_out
  float* awlin   = ws + 7 * T;             // 7200*128 floats
  float* bigbuf  = ws + 7 * T + (long)NTOK * 128;
  float* x1 = Qb;       float* x2 = tgt_tok;
  float* q4 = Kb;       float* off_all = Vb;
  float* attn_out = qk_tok;  float* res = qk_tok;
  float* ca = Ob;       float* pvbuf = bigbuf;  float* f1 = bigbuf;  float* f2 = Kb;

  // 1) transpose inputs to token-major; qk = tgt + qpos
  transpose_in_k<<<dim3(29, 8, 8), dim3(32, 32), 0, stream>>>(tgt, qpos, tgt_tok, qp_tok, qk_tok);

  // 2) Q/K/V projections
  dim3 gg((NTOK + 127) / 128, CDIM / 64, 1);
  gemm_k<0><<<gg, 256, 0, stream>>>(qk_tok, wq, bq, Qb, NTOK, CDIM, CDIM, 0, 0);
  gemm_k<0><<<gg, 256, 0, stream>>>(qk_tok, wk, bk, Kb, NTOK, CDIM, CDIM, 0, 0);
  gemm_k<0><<<gg, 256, 0, stream>>>(tgt_tok, wv, bv, Vb, NTOK, CDIM, CDIM, 0, 0);

  // 3) self-attention
  attn_k<<<dim3(4, 8, 8), 256, 0, stream>>>(Qb, Kb, Vb, Ob);

  // 4) attention output projection
  gemm_k<0><<<gg, 256, 0, stream>>>(Ob, wo, bo, attn_out, NTOK, CDIM, CDIM, 0, 0);

  // 5) x1 = LN(tgt + attn_out; g2,b2)
  ln_k<<<NTOK / 4, 256, 0, stream>>>(tgt_tok, attn_out, g2, b2, x1);

  // 6) q4 = x1 + query_pos
  add_k<<<(int)((T / 4 + 255) / 256), 256, 0, stream>>>(x1, qp_tok, q4, T / 4);

  // 7) sampling offsets (4 levels stacked -> N=256) and attention weights
  gemm_k<0><<<gg, 256, 0, stream>>>(q4, so_w, so_b, off_all, NTOK, 256, 256, 0, 0);
  dim3 ga((NTOK + 127) / 128, 128 / 64, 1);
  gemm_k<0><<<ga, 256, 0, stream>>>(q4, aw_w, aw_b, awlin, NTOK, 128, 256, 0, 0);

  // 8+9) per batch: project all 4 levels into pvbuf (20 MB), then sample.
  {
    const int hw_[4] = {14720, 3680, 920, 240};
    const long lvl_off_[4] = {0L, 14720L * 256, (14720L + 3680) * 256,
                              (14720L + 3680 + 920) * 256};
    for (int b = 0; b < BATCH; ++b) {
      for (int l = 0; l < 4; ++l) {
        const int hw = hw_[l];
        dim3 gv_((hw + 127) / 128, 4, 1);
        gemm_k<1><<<gv_, 256, 0, stream>>>(v[l] + (long)b * 256 * hw,
                                           vp_w + (long)l * 256 * 256, vp_b + l * 256,
                                           pvbuf + lvl_off_[l], hw, 256, 256, hw, 0);
      }
      deform_sample_k<<<QLEN, 256, 0, stream>>>(pvbuf, off_all, awlin, refp, res, b);
    }
  }

  // 10) cross-attn output projection
  gemm_k<0><<<gg, 256, 0, stream>>>(res, op_w, op_b, ca, NTOK, 256, 256, 0, 0);

  // 11) x2 = LN(x1 + ca; g1,b1)
  ln_k<<<NTOK / 4, 256, 0, stream>>>(x1, ca, g1, b1, x2);

  // 12) FFN: f1 = relu(x2@l1), f2 = f1@l2
  dim3 gf1((NTOK + 127) / 128, 1024 / 64, 1);
  gemm_k<0><<<gf1, 256, 0, stream>>>(x2, l1w, l1b, f1, NTOK, 1024, 256, 0, 1);
  gemm_k<0><<<gg, 256, 0, stream>>>(f1, l2w, l2b, f2, NTOK, 256, 1024, 0, 0);

  // 13) out = LN(x2 + f2; g3,b3), written channel-major [B,C,1,Q]
  ln_out_k<<<NTOK / 4, 256, 0, stream>>>(x2, f2, g3, b3, out);
}

// Round 4
// 1501.727 us; speedup vs baseline: 2.3605x; 2.3605x over previous
//
#include <hip/hip_runtime.h>
#include <math.h>

#define QLEN 900
#define CDIM 256
#define BATCH 8
#define NTOK (BATCH * QLEN)   // 7200
#define KSPLIT 4              // attention key-split (900 = 4 * 225)
#define KCH 225

// ---------------------------------------------------------------------------
// Transpose [B,C,Q] -> [B,Q,C] for tgt and query_pos; also qk = tgt + qp.
// ---------------------------------------------------------------------------
__global__ void transpose_in_k(const float* __restrict__ tgt, const float* __restrict__ qp,
                               float* __restrict__ tgt_tok, float* __restrict__ qp_tok,
                               float* __restrict__ qk_tok) {
  __shared__ float t0[32][33];
  __shared__ float t1[32][33];
  const int b  = blockIdx.z;
  const int c0 = blockIdx.y * 32;
  const int q0 = blockIdx.x * 32;
  const int tx = threadIdx.x, ty = threadIdx.y;
  const int q = q0 + tx;
  if (q < QLEN) {
    long i = ((long)(b * CDIM + c0 + ty)) * QLEN + q;
    t0[ty][tx] = tgt[i];
    t1[ty][tx] = qp[i];
  }
  __syncthreads();
  const int qo = q0 + ty;
  if (qo < QLEN) {
    long o = ((long)(b * QLEN + qo)) * CDIM + c0 + tx;
    float a = t0[tx][ty], p = t1[tx][ty];
    tgt_tok[o] = a;
    qp_tok[o]  = p;
    qk_tok[o]  = a + p;
  }
}

// ---------------------------------------------------------------------------
// GEMM core: Out[m][n] = sum_k A(m,k)*W[n][k] + bias[n], optional ReLU.
// Tile 128(M) x 128(N) x 16(K), 256 threads, 8x8 micro-tile.
// ACHAN=0: A row-major [M,K]. ACHAN=1: A(m,k) = A[k*ldA + m].
// N must be a multiple of 128; K a multiple of 16; M guarded.
// ---------------------------------------------------------------------------
template <int ACHAN>
__device__ __forceinline__ void gemm_core(
    const float* __restrict__ A, const float* __restrict__ W,
    const float* __restrict__ bias, float* __restrict__ Out,
    int M, int N, int K, int ldA, int relu, int m0, int n0,
    float (*As)[128], float (*Bs)[128]) {
  const int tid = threadIdx.x;
  const int tx = tid & 15;       // col group 0..15
  const int ty = tid >> 4;       // row group 0..15
  float acc[8][8];
#pragma unroll
  for (int j = 0; j < 8; ++j)
#pragma unroll
    for (int i = 0; i < 8; ++i) acc[j][i] = 0.f;

  for (int k0 = 0; k0 < K; k0 += 16) {
    // ---- stage A tile -> As[k][m]
    if (ACHAN == 0) {
      const int mi = tid >> 1;
      const int k8 = (tid & 1) * 8;
      float4 v0 = make_float4(0.f, 0.f, 0.f, 0.f), v1 = v0;
      if (m0 + mi < M) {
        const float4* p = (const float4*)&A[(long)(m0 + mi) * K + k0 + k8];
        v0 = p[0];
        v1 = p[1];
      }
      As[k8 + 0][mi] = v0.x; As[k8 + 1][mi] = v0.y;
      As[k8 + 2][mi] = v0.z; As[k8 + 3][mi] = v0.w;
      As[k8 + 4][mi] = v1.x; As[k8 + 5][mi] = v1.y;
      As[k8 + 6][mi] = v1.z; As[k8 + 7][mi] = v1.w;
    } else {
      const int mi = tid & 127;
      const int kk0 = (tid >> 7) * 8;
      const int m = m0 + mi;
#pragma unroll
      for (int j = 0; j < 8; ++j) {
        float v = 0.f;
        if (m < M) v = A[(long)(k0 + kk0 + j) * ldA + m];
        As[kk0 + j][mi] = v;
      }
    }
    // ---- stage B tile -> Bs[k][n]  (W row-major [N,K], N%128==0)
    {
      const int ni = tid >> 1;
      const int k8 = (tid & 1) * 8;
      const float4* p = (const float4*)&W[(long)(n0 + ni) * K + k0 + k8];
      const float4 v0 = p[0], v1 = p[1];
      Bs[k8 + 0][ni] = v0.x; Bs[k8 + 1][ni] = v0.y;
      Bs[k8 + 2][ni] = v0.z; Bs[k8 + 3][ni] = v0.w;
      Bs[k8 + 4][ni] = v1.x; Bs[k8 + 5][ni] = v1.y;
      Bs[k8 + 6][ni] = v1.z; Bs[k8 + 7][ni] = v1.w;
    }
    __syncthreads();
#pragma unroll
    for (int kk = 0; kk < 16; ++kk) {
      const float4 a0 = *(const float4*)&As[kk][ty * 4];
      const float4 a1 = *(const float4*)&As[kk][64 + ty * 4];
      const float4 b0 = *(const float4*)&Bs[kk][tx * 4];
      const float4 b1 = *(const float4*)&Bs[kk][64 + tx * 4];
      const float av[8] = {a0.x, a0.y, a0.z, a0.w, a1.x, a1.y, a1.z, a1.w};
      const float bv[8] = {b0.x, b0.y, b0.z, b0.w, b1.x, b1.y, b1.z, b1.w};
#pragma unroll
      for (int j = 0; j < 8; ++j)
#pragma unroll
        for (int i = 0; i < 8; ++i) acc[j][i] += av[j] * bv[i];
    }
    __syncthreads();
  }
  // ---- epilogue
  const float4 bb0 = *(const float4*)&bias[n0 + tx * 4];
  const float4 bb1 = *(const float4*)&bias[n0 + 64 + tx * 4];
  const float bv0[4] = {bb0.x, bb0.y, bb0.z, bb0.w};
  const float bv1[4] = {bb1.x, bb1.y, bb1.z, bb1.w};
#pragma unroll
  for (int j = 0; j < 8; ++j) {
    const int m = m0 + ((j < 4) ? (ty * 4 + j) : (64 + ty * 4 + (j - 4)));
    if (m < M) {
      float o0[4], o1[4];
#pragma unroll
      for (int i = 0; i < 4; ++i) {
        o0[i] = acc[j][i] + bv0[i];
        o1[i] = acc[j][4 + i] + bv1[i];
        if (relu) { o0[i] = fmaxf(o0[i], 0.f); o1[i] = fmaxf(o1[i], 0.f); }
      }
      *(float4*)&Out[(long)m * N + n0 + tx * 4] = make_float4(o0[0], o0[1], o0[2], o0[3]);
      *(float4*)&Out[(long)m * N + n0 + 64 + tx * 4] = make_float4(o1[0], o1[1], o1[2], o1[3]);
    }
  }
}

template <int ACHAN>
__global__ __launch_bounds__(256) void gemm_k(
    const float* __restrict__ A, const float* __restrict__ W,
    const float* __restrict__ bias, float* __restrict__ Out,
    int M, int N, int K, int ldA, int relu) {
  __shared__ float As[16][128];
  __shared__ float Bs[16][128];
  gemm_core<ACHAN>(A, W, bias, Out, M, N, K, ldA, relu,
                   blockIdx.x * 128, blockIdx.y * 128, As, Bs);
}

// Q/K/V projections fused into one launch via grid.z.
__global__ __launch_bounds__(256) void qkv_gemm_k(
    const float* __restrict__ Aqk, const float* __restrict__ Av,
    const float* __restrict__ wq, const float* __restrict__ wk, const float* __restrict__ wv,
    const float* __restrict__ bq, const float* __restrict__ bk, const float* __restrict__ bv,
    float* __restrict__ Qo, float* __restrict__ Ko, float* __restrict__ Vo) {
  __shared__ float As[16][128];
  __shared__ float Bs[16][128];
  const int z = blockIdx.z;
  const float* A = (z < 2) ? Aqk : Av;
  const float* W = (z == 0) ? wq : ((z == 1) ? wk : wv);
  const float* bb = (z == 0) ? bq : ((z == 1) ? bk : bv);
  float* O = (z == 0) ? Qo : ((z == 1) ? Ko : Vo);
  gemm_core<0>(A, W, bb, O, NTOK, CDIM, CDIM, 0, 0,
               blockIdx.x * 128, blockIdx.y * 128, As, Bs);
}

// All 4 pyramid levels of one batch's value projection in one launch.
struct LvlArgs {
  const float* A[4];
  const float* W[4];
  const float* Bv[4];
  float* O[4];
  int hw[4];
  int cum[5];
};
__global__ __launch_bounds__(256) void lvl_gemm_k(LvlArgs la) {
  __shared__ float As[16][128];
  __shared__ float Bs[16][128];
  const int bx = blockIdx.x;
  const int l = (bx >= la.cum[1] ? 1 : 0) + (bx >= la.cum[2] ? 1 : 0) + (bx >= la.cum[3] ? 1 : 0);
  const int m0 = (bx - la.cum[l]) * 128;
  gemm_core<1>(la.A[l], la.W[l], la.Bv[l], la.O[l], la.hw[l], 256, 256, la.hw[l], 0,
               m0, blockIdx.y * 128, As, Bs);
}

// ---------------------------------------------------------------------------
// Self-attention, k-split flash. Partial pass: each block covers 256 queries
// of one (b,h) over one key chunk of 225; per-thread online softmax.
// po[qh][chunk][32] unnormalized; ml[qh*4+chunk] = (m, l).
// grid (4*KSPLIT, H, B): qblk = bx&3, chunk = bx>>2.
// ---------------------------------------------------------------------------
__global__ __launch_bounds__(256) void attn_part_k(
    const float* __restrict__ Q, const float* __restrict__ K,
    const float* __restrict__ V, float* __restrict__ po, float2* __restrict__ ml) {
  __shared__ float Kt[128][32];
  __shared__ float Vt[128][32];
  const int b = blockIdx.z, h = blockIdx.y;
  const int qblk = blockIdx.x & 3, chunk = blockIdx.x >> 2;
  const int q = qblk * 256 + threadIdx.x;
  const bool valid = q < QLEN;
  const int kstart = chunk * KCH, kend = kstart + KCH;

  float qv[32];
  if (valid) {
    const float4* qp4 = (const float4*)&Q[((long)(b * QLEN + q)) * CDIM + h * 32];
#pragma unroll
    for (int i = 0; i < 8; ++i) {
      float4 t = qp4[i];
      qv[4 * i + 0] = t.x; qv[4 * i + 1] = t.y;
      qv[4 * i + 2] = t.z; qv[4 * i + 3] = t.w;
    }
  }
  float mrun = -1e30f, lsum = 0.f;
  float o[32];
#pragma unroll
  for (int d = 0; d < 32; ++d) o[d] = 0.f;

  for (int k0 = kstart; k0 < kend; k0 += 128) {
    const int kn = min(128, kend - k0);
    {
      const int kr = threadIdx.x >> 1;
      const int cb = (threadIdx.x & 1) * 16;
      if (kr < kn) {
        const float4* kp = (const float4*)&K[((long)(b * QLEN + k0 + kr)) * CDIM + h * 32 + cb];
        const float4* vp = (const float4*)&V[((long)(b * QLEN + k0 + kr)) * CDIM + h * 32 + cb];
#pragma unroll
        for (int i = 0; i < 4; ++i) {
          *(float4*)&Kt[kr][cb + 4 * i] = kp[i];
          *(float4*)&Vt[kr][cb + 4 * i] = vp[i];
        }
      }
    }
    __syncthreads();
    if (valid) {
      for (int kk = 0; kk < kn; ++kk) {
        float s0 = 0.f, s1 = 0.f, s2 = 0.f, s3 = 0.f;
        const float* kr = Kt[kk];
#pragma unroll
        for (int d = 0; d < 32; d += 4) {
          s0 += qv[d + 0] * kr[d + 0];
          s1 += qv[d + 1] * kr[d + 1];
          s2 += qv[d + 2] * kr[d + 2];
          s3 += qv[d + 3] * kr[d + 3];
        }
        float s = ((s0 + s1) + (s2 + s3)) * 0.17677669529663687f; // 1/sqrt(32)
        if (s > mrun) {
          const float corr = __expf(mrun - s);
          lsum *= corr;
#pragma unroll
          for (int d = 0; d < 32; ++d) o[d] *= corr;
          mrun = s;
        }
        const float p = __expf(s - mrun);
        lsum += p;
        const float* vr = Vt[kk];
#pragma unroll
        for (int d = 0; d < 32; ++d) o[d] += p * vr[d];
      }
    }
    __syncthreads();
  }
  if (valid) {
    const long qh = ((long)(b * 8 + h)) * QLEN + q;
    float* pp = &po[(qh * KSPLIT + chunk) * 32];
#pragma unroll
    for (int i = 0; i < 8; ++i)
      *(float4*)&pp[4 * i] = make_float4(o[4 * i], o[4 * i + 1], o[4 * i + 2], o[4 * i + 3]);
    ml[qh * KSPLIT + chunk] = make_float2(mrun, lsum);
  }
}

// Combine: 8 query-head pairs per block (32 lanes each, lane = dim).
__global__ __launch_bounds__(256) void attn_combine_k(
    const float* __restrict__ po, const float2* __restrict__ ml, float* __restrict__ O) {
  const long g = (long)blockIdx.x * 8 + (threadIdx.x >> 5);  // qh index < 57600
  const int d = threadIdx.x & 31;
  float2 c0 = ml[g * 4 + 0], c1 = ml[g * 4 + 1], c2 = ml[g * 4 + 2], c3 = ml[g * 4 + 3];
  const float M = fmaxf(fmaxf(c0.x, c1.x), fmaxf(c2.x, c3.x));
  const float w0 = __expf(c0.x - M), w1 = __expf(c1.x - M);
  const float w2 = __expf(c2.x - M), w3 = __expf(c3.x - M);
  const float L = c0.y * w0 + c1.y * w1 + c2.y * w2 + c3.y * w3;
  const float* pp = &po[g * 4 * 32 + d];
  const float ov = (pp[0] * w0 + pp[32] * w1 + pp[64] * w2 + pp[96] * w3) / L;
  const int bq = (int)(g / 7200);
  const int r = (int)(g % 7200);
  const int h = r / QLEN, q = r % QLEN;
  O[((long)(bq * QLEN + q)) * CDIM + h * 32 + d] = ov;
}

// ---------------------------------------------------------------------------
// LayerNorm over channel dim (token-major rows of 256). One wave per token.
// ---------------------------------------------------------------------------
__device__ __forceinline__ void ln_core(const float* __restrict__ A, const float* __restrict__ B,
                                        const float* __restrict__ g, const float* __restrict__ beta,
                                        int tok, int lane, float4& ov, int& c) {
  const float4 av = ((const float4*)&A[(long)tok * CDIM])[lane];
  const float4 bv = ((const float4*)&B[(long)tok * CDIM])[lane];
  const float v0 = av.x + bv.x, v1 = av.y + bv.y, v2 = av.z + bv.z, v3 = av.w + bv.w;
  float s  = v0 + v1 + v2 + v3;
  float ss = v0 * v0 + v1 * v1 + v2 * v2 + v3 * v3;
#pragma unroll
  for (int off = 32; off >= 1; off >>= 1) {
    s  += __shfl_xor(s, off);
    ss += __shfl_xor(ss, off);
  }
  const float mean = s * (1.f / 256.f);
  const float var  = ss * (1.f / 256.f) - mean * mean;
  const float inv  = 1.f / sqrtf(var + 1e-5f);
  c = lane * 4;
  const float4 gv = ((const float4*)g)[lane];
  const float4 bt = ((const float4*)beta)[lane];
  ov.x = (v0 - mean) * inv * gv.x + bt.x;
  ov.y = (v1 - mean) * inv * gv.y + bt.y;
  ov.z = (v2 - mean) * inv * gv.z + bt.z;
  ov.w = (v3 - mean) * inv * gv.w + bt.w;
}

__global__ void ln_k(const float* __restrict__ A, const float* __restrict__ B,
                     const float* __restrict__ g, const float* __restrict__ beta,
                     float* __restrict__ out) {
  const int tok = blockIdx.x * 4 + (threadIdx.x >> 6);
  const int lane = threadIdx.x & 63;
  float4 ov; int c;
  ln_core(A, B, g, beta, tok, lane, ov, c);
  ((float4*)&out[(long)tok * CDIM])[lane] = ov;
}

// LN + also write out2 = LN_result + qp (fused residual-pos add).
__global__ void ln_add_k(const float* __restrict__ A, const float* __restrict__ B,
                         const float* __restrict__ g, const float* __restrict__ beta,
                         const float* __restrict__ qp,
                         float* __restrict__ out, float* __restrict__ out2) {
  const int tok = blockIdx.x * 4 + (threadIdx.x >> 6);
  const int lane = threadIdx.x & 63;
  float4 ov; int c;
  ln_core(A, B, g, beta, tok, lane, ov, c);
  ((float4*)&out[(long)tok * CDIM])[lane] = ov;
  const float4 pv = ((const float4*)&qp[(long)tok * CDIM])[lane];
  float4 o2;
  o2.x = ov.x + pv.x; o2.y = ov.y + pv.y; o2.z = ov.z + pv.z; o2.w = ov.w + pv.w;
  ((float4*)&out2[(long)tok * CDIM])[lane] = o2;
}

// Final LN: writes channel-major output [B,C,1,Q].
__global__ void ln_out_k(const float* __restrict__ A, const float* __restrict__ B,
                         const float* __restrict__ g, const float* __restrict__ beta,
                         float* __restrict__ out) {
  const int tok = blockIdx.x * 4 + (threadIdx.x >> 6);
  const int lane = threadIdx.x & 63;
  float4 ov; int c;
  ln_core(A, B, g, beta, tok, lane, ov, c);
  const int b = tok / QLEN, q = tok - b * QLEN;
  out[((long)(b * CDIM + c + 0)) * QLEN + q] = ov.x;
  out[((long)(b * CDIM + c + 1)) * QLEN + q] = ov.y;
  out[((long)(b * CDIM + c + 2)) * QLEN + q] = ov.z;
  out[((long)(b * CDIM + c + 3)) * QLEN + q] = ov.w;
}

// ---------------------------------------------------------------------------
// Deformable bilinear sampling + aggregation for ONE batch, all 4 levels.
// ---------------------------------------------------------------------------
__global__ __launch_bounds__(256) void deform_sample_k(
    const float* __restrict__ pv, const float* __restrict__ off_all,
    const float* __restrict__ awlin, const float* __restrict__ refp,
    float* __restrict__ res, int bsel) {
  const int gidx = blockIdx.x * 8 + (threadIdx.x >> 5);
  const int d = threadIdx.x & 31;
  const int q = gidx % QLEN;
  const int h = gidx / QLEN;
  const int b = bsel;

  const int vw_[4] = {160, 80, 40, 20};
  const int vh_[4] = {92, 46, 23, 12};
  const long lvl_off_[4] = {0L, 14720L * 256, (14720L + 3680) * 256,
                            (14720L + 3680 + 920) * 256};

  const float* offrow = &off_all[(long)(b * QLEN + q) * 256];
  const float* awrow  = &awlin[(long)(b * QLEN + q) * 128];
  float acc = 0.f;
#pragma unroll
  for (int l = 0; l < 4; ++l) {
    const int vw = vw_[l], vh = vh_[l];
    const float invw = 1.f / (float)vw, invh = 1.f / (float)vh;
    const float* pvl = pv + lvl_off_[l] + h * 32 + d;
#pragma unroll
    for (int p = 0; p < 4; ++p) {
      const float ox = offrow[l * 64 + h * 8 + p * 2 + 0];
      const float oy = offrow[l * 64 + h * 8 + p * 2 + 1];
      const float rx = refp[((long)((b * 32 + h * 4 + p) * 2 + 0)) * QLEN + q];
      const float ry = refp[((long)((b * 32 + h * 4 + p) * 2 + 1)) * QLEN + q];
      float aval = awrow[h * 16 + l * 4 + p];
      aval = 1.f / (1.f + __expf(-aval));
      const float x = (rx + ox * invw) * (float)(vw - 1);
      const float y = (ry + oy * invh) * (float)(vh - 1);
      const float x0f = floorf(x), y0f = floorf(y);
      const float wx1 = x - x0f, wx0 = 1.f - wx1;
      const float wy1 = y - y0f, wy0 = 1.f - wy1;
      const int x0 = (int)x0f, y0 = (int)y0f;
      const int x1 = x0 + 1, y1 = y0 + 1;
      const bool vx0 = (x0 >= 0) & (x0 < vw);
      const bool vx1 = (x1 >= 0) & (x1 < vw);
      const bool vy0 = (y0 >= 0) & (y0 < vh);
      const bool vy1 = (y1 >= 0) & (y1 < vh);
      float s = 0.f;
      if (vx0 & vy0) s += wx0 * wy0 * pvl[(long)(y0 * vw + x0) * 256];
      if (vx1 & vy0) s += wx1 * wy0 * pvl[(long)(y0 * vw + x1) * 256];
      if (vx0 & vy1) s += wx0 * wy1 * pvl[(long)(y1 * vw + x0) * 256];
      if (vx1 & vy1) s += wx1 * wy1 * pvl[(long)(y1 * vw + x1) * 256];
      acc += aval * s;
    }
  }
  res[(long)(b * QLEN + q) * 256 + h * 32 + d] = acc;
}

// ---------------------------------------------------------------------------
extern "C" void kernel_launch(void* const* d_in, const int* in_sizes, int n_in,
                              void* d_out, int out_size, void* d_ws, size_t ws_size,
                              hipStream_t stream) {
  const float* tgt  = (const float*)d_in[0];
  const float* qpos = (const float*)d_in[1];
  const float* refp = (const float*)d_in[2];
  const float* v[4] = {(const float*)d_in[3], (const float*)d_in[4],
                       (const float*)d_in[5], (const float*)d_in[6]};
  const float* so_w = (const float*)d_in[7];
  const float* so_b = (const float*)d_in[8];
  const float* vp_w = (const float*)d_in[9];
  const float* vp_b = (const float*)d_in[10];
  const float* aw_w = (const float*)d_in[11];
  const float* aw_b = (const float*)d_in[12];
  const float* op_w = (const float*)d_in[13];
  const float* op_b = (const float*)d_in[14];
  const float* wq = (const float*)d_in[15]; const float* bq = (const float*)d_in[16];
  const float* wk = (const float*)d_in[17]; const float* bk = (const float*)d_in[18];
  const float* wv = (const float*)d_in[19]; const float* bv = (const float*)d_in[20];
  const float* wo = (const float*)d_in[21]; const float* bo = (const float*)d_in[22];
  const float* g1 = (const float*)d_in[23]; const float* b1 = (const float*)d_in[24];
  const float* g2 = (const float*)d_in[25]; const float* b2 = (const float*)d_in[26];
  const float* g3 = (const float*)d_in[27]; const float* b3 = (const float*)d_in[28];
  const float* l1w = (const float*)d_in[29]; const float* l1b = (const float*)d_in[30];
  const float* l2w = (const float*)d_in[31]; const float* l2b = (const float*)d_in[32];
  float* out = (float*)d_out;

  float* ws = (float*)d_ws;
  const long T = (long)NTOK * CDIM;  // 1,843,200 floats
  const long need = 7 * T + (long)NTOK * 128 + (long)NTOK * 1024;
  if (ws_size < (size_t)need * sizeof(float)) return;  // fail visibly, not fatally

  float* tgt_tok = ws + 0 * T;             // later reused as x2
  float* qp_tok  = ws + 1 * T;
  float* qk_tok  = ws + 2 * T;             // later: attn ml, attn_out, res
  float* Qb      = ws + 3 * T;             // later x1
  float* Kb      = ws + 4 * T;             // later q4, then f2
  float* Vb      = ws + 5 * T;             // later off_all
  float* Ob      = ws + 6 * T;             // attn o, later ca_out
  float* awlin   = ws + 7 * T;             // 7200*128 floats
  float* bigbuf  = ws + 7 * T + (long)NTOK * 128;  // NTOK*1024: po / pvbuf / f1
  float* x1 = Qb;       float* x2 = tgt_tok;
  float* q4 = Kb;       float* off_all = Vb;
  float* attn_out = qk_tok;  float* res = qk_tok;
  float2* ml = (float2*)qk_tok;
  float* ca = Ob;       float* po = bigbuf;  float* pvbuf = bigbuf;
  float* f1 = bigbuf;   float* f2 = Kb;

  // 1) transpose inputs to token-major; qk = tgt + qpos
  transpose_in_k<<<dim3(29, 8, 8), dim3(32, 32), 0, stream>>>(tgt, qpos, tgt_tok, qp_tok, qk_tok);

  // 2) Q/K/V projections (one launch, grid.z = 3)
  qkv_gemm_k<<<dim3(57, 2, 3), 256, 0, stream>>>(qk_tok, tgt_tok, wq, wk, wv,
                                                 bq, bk, bv, Qb, Kb, Vb);

  // 3) self-attention: k-split partials + combine  (po in bigbuf, ml in qk_tok)
  attn_part_k<<<dim3(4 * KSPLIT, 8, 8), 256, 0, stream>>>(Qb, Kb, Vb, po, ml);
  attn_combine_k<<<7200, 256, 0, stream>>>(po, ml, Ob);

  // 4) attention output projection (qk_tok/ml is dead now; write attn_out there)
  gemm_k<0><<<dim3(57, 2), 256, 0, stream>>>(Ob, wo, bo, attn_out, NTOK, CDIM, CDIM, 0, 0);

  // 5) x1 = LN(tgt + attn_out; g2,b2); fused q4 = x1 + query_pos
  ln_add_k<<<NTOK / 4, 256, 0, stream>>>(tgt_tok, attn_out, g2, b2, qp_tok, x1, q4);

  // 6) sampling offsets (4 levels stacked -> N=256) and attention weights
  gemm_k<0><<<dim3(57, 2), 256, 0, stream>>>(q4, so_w, so_b, off_all, NTOK, 256, 256, 0, 0);
  gemm_k<0><<<dim3(57, 1), 256, 0, stream>>>(q4, aw_w, aw_b, awlin, NTOK, 128, 256, 0, 0);

  // 7) per batch: project all 4 levels into pvbuf (one launch), then sample.
  {
    const int hw_[4] = {14720, 3680, 920, 240};
    const long lvl_off_[4] = {0L, 14720L * 256, (14720L + 3680) * 256,
                              (14720L + 3680 + 920) * 256};
    LvlArgs la;
    la.cum[0] = 0; la.cum[1] = 115; la.cum[2] = 144; la.cum[3] = 152; la.cum[4] = 154;
    for (int l = 0; l < 4; ++l) {
      la.W[l] = vp_w + (long)l * 256 * 256;
      la.Bv[l] = vp_b + l * 256;
      la.O[l] = pvbuf + lvl_off_[l];
      la.hw[l] = hw_[l];
    }
    for (int b = 0; b < BATCH; ++b) {
      for (int l = 0; l < 4; ++l) la.A[l] = v[l] + (long)b * 256 * hw_[l];
      lvl_gemm_k<<<dim3(154, 2), 256, 0, stream>>>(la);
      deform_sample_k<<<QLEN, 256, 0, stream>>>(pvbuf, off_all, awlin, refp, res, b);
    }
  }

  // 8) cross-attn output projection
  gemm_k<0><<<dim3(57, 2), 256, 0, stream>>>(res, op_w, op_b, ca, NTOK, 256, 256, 0, 0);

  // 9) x2 = LN(x1 + ca; g1,b1)
  ln_k<<<NTOK / 4, 256, 0, stream>>>(x1, ca, g1, b1, x2);

  // 10) FFN: f1 = relu(x2@l1), f2 = f1@l2
  gemm_k<0><<<dim3(57, 8), 256, 0, stream>>>(x2, l1w, l1b, f1, NTOK, 1024, 256, 0, 1);
  gemm_k<0><<<dim3(57, 2), 256, 0, stream>>>(f1, l2w, l2b, f2, NTOK, 256, 1024, 0, 0);

  // 11) out = LN(x2 + f2; g3,b3), written channel-major [B,C,1,Q]
  ln_out_k<<<NTOK / 4, 256, 0, stream>>>(x2, f2, g3, b3, out);
}